// Round 6
// baseline (191.449 us; speedup 1.0000x reference)
//
#include <hip/hip_runtime.h>
#include <hip/hip_bf16.h>

typedef __attribute__((ext_vector_type(8))) short short8;
typedef __attribute__((ext_vector_type(4))) float f32x4;

__device__ __forceinline__ unsigned short f2bf(float x) {
    unsigned int u = __float_as_uint(x);
    unsigned int lsb = (u >> 16) & 1u;
    u += 0x7fffu + lsb;                    // round-to-nearest-even
    return (unsigned short)(u >> 16);
}

__device__ __forceinline__ short8 pack8(f32x4 a, f32x4 b) {
    short8 r;
    r[0] = (short)f2bf(a.x); r[1] = (short)f2bf(a.y);
    r[2] = (short)f2bf(a.z); r[3] = (short)f2bf(a.w);
    r[4] = (short)f2bf(b.x); r[5] = (short)f2bf(b.y);
    r[6] = (short)f2bf(b.z); r[7] = (short)f2bf(b.w);
    return r;
}

// Standalone init (fallback path): out[n][c] = bias[c]
__global__ __launch_bounds__(256) void k_init(const float* __restrict__ bias,
                                              float* __restrict__ out, long total4) {
    long i4 = (long)blockIdx.x * 256 + threadIdx.x;
    if (i4 < total4) {
        const f32x4* b4 = (const f32x4*)bias;
        ((f32x4*)out)[i4] = b4[i4 & 15];
    }
}

// Fused: blocks [0,gblocks) compute G = (feat @ W.T) in bf16 via MFMA;
// blocks [gblocks, ...) broadcast bias into out. G is FLAT [N][64] bf16.
// NOTE: out init must be a PLAIN store — NT store streamed it to HBM and made
// every later atomic flush RMW against HBM (R4: WRITE_SIZE doubled, +22 us).
__global__ __launch_bounds__(256) void k_setup(const float* __restrict__ feat,
                                               const float* __restrict__ W,
                                               const float* __restrict__ bias,
                                               unsigned short* __restrict__ G,
                                               float* __restrict__ out,
                                               int N, int gblocks) {
    if ((int)blockIdx.x >= gblocks) {
        long i4 = (long)(blockIdx.x - gblocks) * 256 + threadIdx.x;
        long total4 = (long)N * 16;            // N*64 floats / 4
        if (i4 < total4) {
            const f32x4* b4 = (const f32x4*)bias;
            ((f32x4*)out)[i4] = b4[i4 & 15];   // plain store: stay dirty in L2
        }
        return;
    }

    int wave = blockIdx.x * 4 + (threadIdx.x >> 6);
    int lane = threadIdx.x & 63;
    int m0 = wave * 16;
    if (m0 >= N) return;
    int n = lane & 15;
    int quad = lane >> 4;

    // B fragments: B[k][c0+n] = W[c0+n][k]; k = ks*32 + quad*8 + j
    short8 bf[4][2];
#pragma unroll
    for (int ct = 0; ct < 4; ++ct)
#pragma unroll
        for (int ks = 0; ks < 2; ++ks) {
            const f32x4* wp = (const f32x4*)(W + (size_t)(ct * 16 + n) * 64 + ks * 32 + quad * 8);
            f32x4 w0 = wp[0];
            f32x4 w1 = wp[1];
            bf[ct][ks] = pack8(w0, w1);
        }

    // A fragments: A[m0+n][k]  (NT load: feat read exactly once)
    int mrow = m0 + n; if (mrow >= N) mrow = N - 1;
    short8 af[2];
#pragma unroll
    for (int ks = 0; ks < 2; ++ks) {
        const f32x4* ap = (const f32x4*)(feat + (size_t)mrow * 64 + ks * 32 + quad * 8);
        f32x4 a0 = __builtin_nontemporal_load(ap);
        f32x4 a1 = __builtin_nontemporal_load(ap + 1);
        af[ks] = pack8(a0, a1);
    }

    f32x4 acc[4];
#pragma unroll
    for (int ct = 0; ct < 4; ++ct) {
        acc[ct] = (f32x4){0.f, 0.f, 0.f, 0.f};
#pragma unroll
        for (int ks = 0; ks < 2; ++ks)
            acc[ct] = __builtin_amdgcn_mfma_f32_16x16x32_bf16(af[ks], bf[ct][ks], acc[ct], 0, 0, 0);
    }

    // D layout: col = lane&15 (=n), row = quad*4 + reg. Plain stores: G is
    // re-read by k_spmm, keep it in L2/L3.
#pragma unroll
    for (int ct = 0; ct < 4; ++ct)
#pragma unroll
        for (int r = 0; r < 4; ++r) {
            int rowm = m0 + quad * 4 + r;
            if (rowm < N)
                G[(size_t)rowm * 64 + ct * 16 + n] = f2bf(acc[ct][r]);
        }
}

// SpMM: out[row] += val * G[col]. Sorted rows. 256 edges/wave, TWO passes
// (fg = feature half), fg pinned to XCD quads.
// R14 model (R5 counters): bound by per-CU outstanding-L2-miss capacity x
// miss latency (L2-miss mix at 3.16 TB/s while streaming does 6.3 through
// the same path; true HBM only ~1.2 TB/s; occupancy 52%; ~30 miss-lines in
// flight/CU). fg-pinning is load-bearing (6.4 MB ws -> ~60% L2 hit; FETCH
// 161 MB vs predicted ~280 unpinned) — kept verbatim. This round raises
// misses-in-flight on both axes:
//  - prefetch depth 2 -> 3 groups (4-slot rolling buffer, 24-32 gather
//    instrs = 96-128 lines in flight per wave)
//  - __launch_bounds__(256, 8): pin 8 waves/SIMD (also guards the 64-VGPR
//    occupancy cliff with the extra buffer slot)
// Everything else identical to R5: single fully-used 64B line per edge-pass
// (line 2c+fg = feats [32fg,32fg+32) of col c), 4 edges x 16 lanes x dword
// per instruction, ballot boundary masks in SGPRs, branch-free interior
// fast path, shfl_xor(16/32) quarter-reduce flush, plain bias+acc store for
// interior rows / atomicAdd for first+last possibly-shared rows.
__global__ __launch_bounds__(256, 8) void k_spmm(const unsigned short* __restrict__ G,
                                                 const int* __restrict__ erow,
                                                 const int* __restrict__ ecol,
                                                 const float* __restrict__ evalv,
                                                 const float* __restrict__ bias,
                                                 float* __restrict__ out, int E) {
    int b = blockIdx.x;
    int fg  = (b & 7) >> 2;                 // XCD quad -> feature half
    int sub = (b >> 3) * 4 + (b & 3);       // block index within this fg
    int wavein = threadIdx.x >> 6;
    int lane = threadIdx.x & 63;
    long base0 = ((long)sub * 4 + wavein) * 256;
    if (base0 >= E) return;

    int q  = lane >> 4;                     // edge slot within 4-edge pack
    int fs = lane & 15;                     // feature-dword within 32-feat half
    int vq4 = q << 2;                       // bpermute byte base for quarter
    unsigned voff = (unsigned)fs * 4u;      // byte offset within 64B half-row
    const char* Gb = (const char*)G + ((unsigned)fg << 6);
    float2 b2 = ((const float2*)bias)[fg * 16 + fs];

    float acc0 = 0.f, acc1 = 0.f;
    bool first = true;                      // first row may be shared w/ prev wave
    int cur;

    auto flush_atomic = [&]() {
        float t0 = acc0 + __shfl_xor(acc0, 16);
        float t1 = acc1 + __shfl_xor(acc1, 16);
        t0 += __shfl_xor(t0, 32);
        t1 += __shfl_xor(t1, 32);
        if (lane < 16) {
            float* p = out + ((size_t)(unsigned)cur << 6) + (unsigned)(fg * 32 + fs * 2);
            atomicAdd(p, t0);
            atomicAdd(p + 1, t1);
        }
        acc0 = 0.f; acc1 = 0.f;
    };
    auto flush = [&]() {
        if (first) { flush_atomic(); first = false; return; }
        float t0 = acc0 + __shfl_xor(acc0, 16);
        float t1 = acc1 + __shfl_xor(acc1, 16);
        t0 += __shfl_xor(t0, 32);
        t1 += __shfl_xor(t1, 32);
        if (lane < 16) {
            float* p = out + ((size_t)(unsigned)cur << 6) + (unsigned)(fg * 32 + fs * 2);
            float2 o; o.x = b2.x + t0; o.y = b2.y + t1;
            *(float2*)p = o;
        }
        acc0 = 0.f; acc1 = 0.f;
    };

    if (base0 + 256 <= E) {
        // ---- fast path: full 256-edge segment ----
        long i0 = base0 + lane;
        int rv[4], cv[4], vvv[4];
#pragma unroll
        for (int c = 0; c < 4; ++c) {
            rv[c]  = __builtin_nontemporal_load(erow + i0 + 64 * c);
            cv[c]  = __builtin_nontemporal_load(ecol + i0 + 64 * c);
            vvv[c] = __builtin_nontemporal_load((const int*)evalv + i0 + 64 * c);
        }
        cur = __builtin_amdgcn_readlane(rv[0], 0);

        // boundary masks: bit e of bm[c] = row[e] != row[e+1] within chunk c;
        // bit 63 = boundary between chunk c and c+1 (forced at segment end)
        unsigned long long bm[4];
#pragma unroll
        for (int c = 0; c < 4; ++c) {
            int rn = __shfl_down(rv[c], 1);
            unsigned long long m = __ballot(rv[c] != rn) & 0x7fffffffffffffffULL;
            int r63 = __builtin_amdgcn_readlane(rv[c], 63);
            int n0  = (c < 3) ? __builtin_amdgcn_readlane(rv[c + 1], 0) : (r63 + 1);
            if (r63 != n0) m |= 0x8000000000000000ULL;
            bm[c] = m;
        }

        unsigned gbuf[4][8];                // 4-slot rolling buffer of line-gathers

#define SPMM_ISSUE(GI, SLOT) do {                                              \
    _Pragma("unroll")                                                          \
    for (int k_ = 0; k_ < 8; ++k_) {                                           \
        const int p_  = (GI) * 8 + k_;      /* pack index 0..63 */             \
        const int c_  = p_ >> 4;            /* chunk */                        \
        const int pj_ = p_ & 15;            /* pack within chunk */            \
        int idx_ = vq4 + 16 * pj_;                                             \
        int colv_ = __builtin_amdgcn_ds_bpermute(idx_, cv[c_]);                \
        unsigned off_ = ((unsigned)colv_ << 7) + voff;                         \
        gbuf[SLOT][k_] = *(const unsigned*)(Gb + off_);                        \
    } } while (0)

        // prologue: three groups (96 lines) in flight before first consume
        SPMM_ISSUE(0, 0);
        SPMM_ISSUE(1, 1);
        SPMM_ISSUE(2, 2);

#pragma unroll
        for (int g = 0; g < 8; ++g) {
            if (g < 5) SPMM_ISSUE(g + 3, (g + 3) & 3);
            __builtin_amdgcn_sched_barrier(0);   // keep issue ahead of consume

#pragma unroll
            for (int k = 0; k < 8; ++k) {
                const int p  = g * 8 + k;        // pack index 0..63
                const int c  = p >> 4;           // chunk
                const int pj = p & 15;           // pack within chunk
                const int i4 = pj * 4;           // first edge-lane of pack
                int idx = vq4 + i4 * 4;
                float vs = __int_as_float(__builtin_amdgcn_ds_bpermute(idx, vvv[c]));
                unsigned u = gbuf[g & 3][k];
                float flo = __uint_as_float(u << 16);
                float fhi = __uint_as_float(u & 0xffff0000u);
                bool slow = (pj == 0) ? ((c > 0 && ((bm[c - 1] >> 63) & 1ULL)) || (bm[c] & 7ULL) != 0)
                                      : (((bm[c] >> (4 * pj - 1)) & 0xFULL) != 0);
                if (!slow) {
                    acc0 = fmaf(vs, flo, acc0);
                    acc1 = fmaf(vs, fhi, acc1);
                } else {
                    int r0 = __builtin_amdgcn_readlane(rv[c], i4);
                    int r3 = __builtin_amdgcn_readlane(rv[c], i4 + 3);
                    if (r0 == r3) {
                        if (r0 != cur) { flush(); cur = r0; }
                        acc0 = fmaf(vs, flo, acc0);
                        acc1 = fmaf(vs, fhi, acc1);
                    } else {
                        int rowsv = __builtin_amdgcn_ds_bpermute(idx, rv[c]);
                        int r1 = __builtin_amdgcn_readlane(rv[c], i4 + 1);
                        int r2 = __builtin_amdgcn_readlane(rv[c], i4 + 2);
                        int rr = r0;
                        while (true) {
                            if (rr != cur) { flush(); cur = rr; }
                            float vm = (rowsv == rr) ? vs : 0.f;
                            acc0 = fmaf(vm, flo, acc0);
                            acc1 = fmaf(vm, fhi, acc1);
                            if (rr == r3) break;
                            rr = (r1 > rr) ? r1 : ((r2 > rr) ? r2 : r3);
                        }
                    }
                }
            }
        }
#undef SPMM_ISSUE
    } else {
        // ---- tail path: generic per-edge loop (quarter 0 accumulates) ----
        cur = erow[base0];
        for (long e = base0; e < (long)E; ++e) {
            int r = erow[e];
            int c = ecol[e];
            float v = evalv[e];
            unsigned u = *(const unsigned*)(Gb + (((unsigned)c << 7) + voff));
            float flo = __uint_as_float(u << 16);
            float fhi = __uint_as_float(u & 0xffff0000u);
            if (r != cur) { flush(); cur = r; }
            float vm = (q == 0) ? v : 0.f;
            acc0 = fmaf(vm, flo, acc0);
            acc1 = fmaf(vm, fhi, acc1);
        }
    }

    // last row may be shared with the next wave -> always atomic
    flush_atomic();
}

// Fallback if ws too small: fused f32 gather + shfl transform at flush.
__global__ __launch_bounds__(256) void k_fused(const float* __restrict__ feat,
                                               const int* __restrict__ erow,
                                               const int* __restrict__ ecol,
                                               const float* __restrict__ evalv,
                                               const float* __restrict__ W,
                                               float* __restrict__ out,
                                               int E, int epw) {
    __shared__ float Wt[64 * 64];
    for (int i = threadIdx.x; i < 4096; i += 256) {
        int c = i >> 6, f = i & 63;
        Wt[f * 64 + c] = W[i];
    }
    __syncthreads();

    int wave = blockIdx.x * 4 + (threadIdx.x >> 6);
    int lane = threadIdx.x & 63;
    long e0 = (long)wave * epw;
    if (e0 >= E) return;
    long e1 = e0 + epw; if (e1 > E) e1 = E;

    int cur = erow[e0];
    float acc = 0.f;
    for (long e = e0; e < e1; ++e) {
        int r = erow[e];
        int c = ecol[e];
        float v = evalv[e];
        float g = feat[((size_t)c << 6) | lane];
        if (r != cur) {
            float res = 0.f;
#pragma unroll
            for (int f = 0; f < 64; ++f)
                res += __shfl(acc, f, 64) * Wt[f * 64 + lane];
            atomicAdd(out + ((size_t)cur << 6) + lane, res);
            acc = 0.f;
            cur = r;
        }
        acc += v * g;
    }
    {
        float res = 0.f;
#pragma unroll
        for (int f = 0; f < 64; ++f)
            res += __shfl(acc, f, 64) * Wt[f * 64 + lane];
        atomicAdd(out + ((size_t)cur << 6) + lane, res);
    }
}

extern "C" void kernel_launch(void* const* d_in, const int* in_sizes, int n_in,
                              void* d_out, int out_size, void* d_ws, size_t ws_size,
                              hipStream_t stream) {
    const float* feat  = (const float*)d_in[0];
    const int*   erow  = (const int*)d_in[1];
    const int*   ecol  = (const int*)d_in[2];
    const float* evalv = (const float*)d_in[3];
    const float* W     = (const float*)d_in[4];
    const float* bias  = (const float*)d_in[5];
    float* out = (float*)d_out;

    int N = in_sizes[0] / 64;
    int E = in_sizes[1];

    size_t need = (size_t)N * 64 * sizeof(unsigned short);
    if (ws_size >= need) {
        unsigned short* G = (unsigned short*)d_ws;
        int tiles = (N + 15) / 16;
        int gblocks = (tiles + 3) / 4;
        long total4 = (long)N * 16;
        int iblocks = (int)((total4 + 255) / 256);
        k_setup<<<gblocks + iblocks, 256, 0, stream>>>(feat, W, bias, G, out, N, gblocks);

        // 2 feature-halves x (E/256) waves; octets of 8 blocks give 4 blocks
        // to each XCD quad, so each quad's L2 works one 6.4 MB half of G.
        int nwpf = (E + 255) / 256;        // segments (waves) per feature-half
        int bpf  = (nwpf + 3) / 4;         // blocks per feature-half
        int noct = (bpf + 3) / 4;          // octets: 4 blocks per half each
        k_spmm<<<noct * 8, 256, 0, stream>>>(G, erow, ecol, evalv, bias, out, E);
    } else {
        long total4 = (long)N * 16;
        k_init<<<(int)((total4 + 255) / 256), 256, 0, stream>>>(bias, out, total4);
        int epw = (E + 8191) / 8192;
        if (epw < 32) epw = 32;
        int nwaves = (E + epw - 1) / epw;
        int nblocks = (nwaves + 3) / 4;
        k_fused<<<nblocks, 256, 0, stream>>>(feat, erow, ecol, evalv, W, out, E, epw);
    }
}

// Round 8
// 158.840 us; speedup vs baseline: 1.2053x; 1.2053x over previous
//
#include <hip/hip_runtime.h>
#include <hip/hip_bf16.h>

typedef __attribute__((ext_vector_type(8))) short short8;
typedef __attribute__((ext_vector_type(4))) float f32x4;

__device__ __forceinline__ unsigned short f2bf(float x) {
    unsigned int u = __float_as_uint(x);
    unsigned int lsb = (u >> 16) & 1u;
    u += 0x7fffu + lsb;                    // round-to-nearest-even
    return (unsigned short)(u >> 16);
}

__device__ __forceinline__ short8 pack8(f32x4 a, f32x4 b) {
    short8 r;
    r[0] = (short)f2bf(a.x); r[1] = (short)f2bf(a.y);
    r[2] = (short)f2bf(a.z); r[3] = (short)f2bf(a.w);
    r[4] = (short)f2bf(b.x); r[5] = (short)f2bf(b.y);
    r[6] = (short)f2bf(b.z); r[7] = (short)f2bf(b.w);
    return r;
}

// Standalone init (fallback path): out[n][c] = bias[c]
__global__ __launch_bounds__(256) void k_init(const float* __restrict__ bias,
                                              float* __restrict__ out, long total4) {
    long i4 = (long)blockIdx.x * 256 + threadIdx.x;
    if (i4 < total4) {
        const f32x4* b4 = (const f32x4*)bias;
        ((f32x4*)out)[i4] = b4[i4 & 15];
    }
}

// Fused: blocks [0,gblocks) compute G8 = per-row-scaled-int8(feat @ W.T) via
// MFMA; blocks [gblocks, ...) broadcast bias into out.
// R16: R7's fp8 kept the 64B-one-line-per-row layout but failed accuracy
// (absmax 0.029 > 0.018): e4m3 error is RELATIVE (~3.6% of |G|), and the
// |G|~2-3 tails dominate. Per-row-scaled int8 keeps the layout and gives a
// UNIFORM step rowmax/127 (~6x lower rms on tails): predicted absmax ~0.008.
// scales[N] (f32, 400KB) lives after G8 in ws; k_spmm folds scale into the
// edge value at preload (val*scale[col] — both per-edge), so the hot loop
// is unchanged.
// NOTE: out init must be a PLAIN store — NT store streamed it to HBM and made
// every later atomic flush RMW against HBM (R4: WRITE_SIZE doubled, +22 us).
__global__ __launch_bounds__(256) void k_setup(const float* __restrict__ feat,
                                               const float* __restrict__ W,
                                               const float* __restrict__ bias,
                                               unsigned char* __restrict__ G8,
                                               float* __restrict__ scales,
                                               float* __restrict__ out,
                                               int N, int gblocks) {
    if ((int)blockIdx.x >= gblocks) {
        long i4 = (long)(blockIdx.x - gblocks) * 256 + threadIdx.x;
        long total4 = (long)N * 16;            // N*64 floats / 4
        if (i4 < total4) {
            const f32x4* b4 = (const f32x4*)bias;
            ((f32x4*)out)[i4] = b4[i4 & 15];   // plain store: stay dirty in L2
        }
        return;
    }

    int wave = blockIdx.x * 4 + (threadIdx.x >> 6);
    int lane = threadIdx.x & 63;
    int m0 = wave * 16;
    if (m0 >= N) return;
    int n = lane & 15;
    int quad = lane >> 4;

    // B fragments: B[k][c0+n] = W[c0+n][k]; k = ks*32 + quad*8 + j
    short8 bf[4][2];
#pragma unroll
    for (int ct = 0; ct < 4; ++ct)
#pragma unroll
        for (int ks = 0; ks < 2; ++ks) {
            const f32x4* wp = (const f32x4*)(W + (size_t)(ct * 16 + n) * 64 + ks * 32 + quad * 8);
            f32x4 w0 = wp[0];
            f32x4 w1 = wp[1];
            bf[ct][ks] = pack8(w0, w1);
        }

    // A fragments: A[m0+n][k]  (NT load: feat read exactly once)
    int mrow = m0 + n; if (mrow >= N) mrow = N - 1;
    short8 af[2];
#pragma unroll
    for (int ks = 0; ks < 2; ++ks) {
        const f32x4* ap = (const f32x4*)(feat + (size_t)mrow * 64 + ks * 32 + quad * 8);
        f32x4 a0 = __builtin_nontemporal_load(ap);
        f32x4 a1 = __builtin_nontemporal_load(ap + 1);
        af[ks] = pack8(a0, a1);
    }

    f32x4 acc[4];
#pragma unroll
    for (int ct = 0; ct < 4; ++ct) {
        acc[ct] = (f32x4){0.f, 0.f, 0.f, 0.f};
#pragma unroll
        for (int ks = 0; ks < 2; ++ks)
            acc[ct] = __builtin_amdgcn_mfma_f32_16x16x32_bf16(af[ks], bf[ct][ks], acc[ct], 0, 0, 0);
    }

    // D layout: col = lane&15 (=n), row = quad*4 + reg.
    // Per row (quad,r): rowmax over ct (in-lane) and n (shfl_xor within the
    // 16-lane group) -> scale = rowmax/127; quantize q = rint(G*127/rowmax).
#pragma unroll
    for (int r = 0; r < 4; ++r) {
        float rm = fmaxf(fmaxf(fabsf(acc[0][r]), fabsf(acc[1][r])),
                         fmaxf(fabsf(acc[2][r]), fabsf(acc[3][r])));
        rm = fmaxf(rm, __shfl_xor(rm, 1, 16));
        rm = fmaxf(rm, __shfl_xor(rm, 2, 16));
        rm = fmaxf(rm, __shfl_xor(rm, 4, 16));
        rm = fmaxf(rm, __shfl_xor(rm, 8, 16));
        int rowm = m0 + quad * 4 + r;
        if (rowm < N) {
            float inv = (rm > 0.f) ? (127.f / rm) : 0.f;
            if (n == 0) scales[rowm] = rm * (1.f / 127.f);
#pragma unroll
            for (int ct = 0; ct < 4; ++ct) {
                float qf = rintf(acc[ct][r] * inv);
                qf = fminf(127.f, fmaxf(-127.f, qf));
                G8[(size_t)rowm * 64 + ct * 16 + n] = (unsigned char)(signed char)(int)qf;
            }
        }
    }
}

// SpMM: out[row] += val*scale[col] * q8[col]. Sorted rows. 256 edges/wave,
// ONE pass. R16 model (R5/R6): miss path (L2<->L3 fabric) saturates at
// ~3.3 TB/s regardless of occupancy/depth; transactions & bytes are the
// currency. int8 rows are ONE 64B line -> 1.6M transactions (vs bf16 3.2M),
// metadata read once, ws 6.8 MB/XCD. Structure R5-verbatim: 4 edges x 16
// lanes x dword per gather instruction (4 fully-used lines), 8-pack groups
// issued 2 ahead (3-slot rolling buffer; NO launch_bounds min-waves — R6's
// cap spilled to scratch), ballot boundary masks in SGPRs, branch-free
// interior fast path. scale folded into vvv at preload (per-edge product).
// Flush: shfl_xor(16/32) quarter-reduce, lanes 0-15 write float4: plain
// bias+acc store interior, atomicAdd first/last possibly-shared rows.
__global__ __launch_bounds__(256) void k_spmm(const unsigned char* __restrict__ G8,
                                              const float* __restrict__ scales,
                                              const int* __restrict__ erow,
                                              const int* __restrict__ ecol,
                                              const float* __restrict__ evalv,
                                              const float* __restrict__ bias,
                                              float* __restrict__ out, int E) {
    int wave = blockIdx.x * 4 + (threadIdx.x >> 6);
    int lane = threadIdx.x & 63;
    long base0 = (long)wave * 256;
    if (base0 >= E) return;

    int q  = lane >> 4;                     // edge slot within 4-edge pack
    int fs = lane & 15;                     // feature-dword: feats [4fs,4fs+4)
    int vq4 = q << 2;                       // bpermute byte base for quarter
    unsigned voff = (unsigned)fs * 4u;      // byte offset within 64B row
    f32x4 b4 = ((const f32x4*)bias)[fs];

    float acc0 = 0.f, acc1 = 0.f, acc2 = 0.f, acc3 = 0.f;
    bool first = true;                      // first row may be shared w/ prev wave
    int cur;

    auto flush_atomic = [&]() {
        float t0 = acc0 + __shfl_xor(acc0, 16);
        float t1 = acc1 + __shfl_xor(acc1, 16);
        float t2 = acc2 + __shfl_xor(acc2, 16);
        float t3 = acc3 + __shfl_xor(acc3, 16);
        t0 += __shfl_xor(t0, 32); t1 += __shfl_xor(t1, 32);
        t2 += __shfl_xor(t2, 32); t3 += __shfl_xor(t3, 32);
        if (lane < 16) {
            float* p = out + ((size_t)(unsigned)cur << 6) + ((unsigned)fs << 2);
            atomicAdd(p + 0, t0);
            atomicAdd(p + 1, t1);
            atomicAdd(p + 2, t2);
            atomicAdd(p + 3, t3);
        }
        acc0 = acc1 = acc2 = acc3 = 0.f;
    };
    auto flush = [&]() {
        if (first) { flush_atomic(); first = false; return; }
        float t0 = acc0 + __shfl_xor(acc0, 16);
        float t1 = acc1 + __shfl_xor(acc1, 16);
        float t2 = acc2 + __shfl_xor(acc2, 16);
        float t3 = acc3 + __shfl_xor(acc3, 16);
        t0 += __shfl_xor(t0, 32); t1 += __shfl_xor(t1, 32);
        t2 += __shfl_xor(t2, 32); t3 += __shfl_xor(t3, 32);
        if (lane < 16) {
            float* p = out + ((size_t)(unsigned)cur << 6) + ((unsigned)fs << 2);
            f32x4 o = {b4.x + t0, b4.y + t1, b4.z + t2, b4.w + t3};
            *(f32x4*)p = o;
        }
        acc0 = acc1 = acc2 = acc3 = 0.f;
    };

    if (base0 + 256 <= E) {
        // ---- fast path: full 256-edge segment ----
        long i0 = base0 + lane;
        int rv[4], cv[4], vvv[4];
#pragma unroll
        for (int c = 0; c < 4; ++c) {
            rv[c]  = __builtin_nontemporal_load(erow + i0 + 64 * c);
            cv[c]  = __builtin_nontemporal_load(ecol + i0 + 64 * c);
            vvv[c] = __builtin_nontemporal_load((const int*)evalv + i0 + 64 * c);
            // fold per-col scale into the edge value (scales: 400KB, L2-hot)
            float sc = scales[(unsigned)cv[c]];
            vvv[c] = __float_as_int(__int_as_float(vvv[c]) * sc);
        }
        cur = __builtin_amdgcn_readlane(rv[0], 0);

        // boundary masks: bit e of bm[c] = row[e] != row[e+1] within chunk c;
        // bit 63 = boundary between chunk c and c+1 (forced at segment end)
        unsigned long long bm[4];
#pragma unroll
        for (int c = 0; c < 4; ++c) {
            int rn = __shfl_down(rv[c], 1);
            unsigned long long m = __ballot(rv[c] != rn) & 0x7fffffffffffffffULL;
            int r63 = __builtin_amdgcn_readlane(rv[c], 63);
            int n0  = (c < 3) ? __builtin_amdgcn_readlane(rv[c + 1], 0) : (r63 + 1);
            if (r63 != n0) m |= 0x8000000000000000ULL;
            bm[c] = m;
        }

        unsigned gbuf[3][8];                // 3-slot rolling buffer of line-gathers

#define SPMM_ISSUE(GI, SLOT) do {                                              \
    _Pragma("unroll")                                                          \
    for (int k_ = 0; k_ < 8; ++k_) {                                           \
        const int p_  = (GI) * 8 + k_;      /* pack index 0..63 */             \
        const int c_  = p_ >> 4;            /* chunk */                        \
        const int pj_ = p_ & 15;            /* pack within chunk */            \
        int idx_ = vq4 + 16 * pj_;                                             \
        int colv_ = __builtin_amdgcn_ds_bpermute(idx_, cv[c_]);                \
        unsigned off_ = ((unsigned)colv_ << 6) + voff;                         \
        gbuf[SLOT][k_] = *(const unsigned*)(G8 + off_);                        \
    } } while (0)

        // prologue: two groups (64 lines) in flight before first consume
        SPMM_ISSUE(0, 0);
        SPMM_ISSUE(1, 1);

#pragma unroll
        for (int g = 0; g < 8; ++g) {
            if (g < 6) SPMM_ISSUE(g + 2, (g + 2) % 3);
            __builtin_amdgcn_sched_barrier(0);   // keep issue ahead of consume

#pragma unroll
            for (int k = 0; k < 8; ++k) {
                const int p  = g * 8 + k;        // pack index 0..63
                const int c  = p >> 4;           // chunk
                const int pj = p & 15;           // pack within chunk
                const int i4 = pj * 4;           // first edge-lane of pack
                int idx = vq4 + i4 * 4;
                float vs = __int_as_float(__builtin_amdgcn_ds_bpermute(idx, vvv[c]));
                unsigned u = gbuf[g % 3][k];
                float f0 = (float)((int)(u << 24) >> 24);
                float f1 = (float)((int)(u << 16) >> 24);
                float f2 = (float)((int)(u << 8) >> 24);
                float f3 = (float)((int)u >> 24);
                bool slow = (pj == 0) ? ((c > 0 && ((bm[c - 1] >> 63) & 1ULL)) || (bm[c] & 7ULL) != 0)
                                      : (((bm[c] >> (4 * pj - 1)) & 0xFULL) != 0);
                if (!slow) {
                    acc0 = fmaf(vs, f0, acc0);
                    acc1 = fmaf(vs, f1, acc1);
                    acc2 = fmaf(vs, f2, acc2);
                    acc3 = fmaf(vs, f3, acc3);
                } else {
                    int r0 = __builtin_amdgcn_readlane(rv[c], i4);
                    int r3 = __builtin_amdgcn_readlane(rv[c], i4 + 3);
                    if (r0 == r3) {
                        if (r0 != cur) { flush(); cur = r0; }
                        acc0 = fmaf(vs, f0, acc0);
                        acc1 = fmaf(vs, f1, acc1);
                        acc2 = fmaf(vs, f2, acc2);
                        acc3 = fmaf(vs, f3, acc3);
                    } else {
                        int rowsv = __builtin_amdgcn_ds_bpermute(idx, rv[c]);
                        int r1 = __builtin_amdgcn_readlane(rv[c], i4 + 1);
                        int r2 = __builtin_amdgcn_readlane(rv[c], i4 + 2);
                        int rr = r0;
                        while (true) {
                            if (rr != cur) { flush(); cur = rr; }
                            float vm = (rowsv == rr) ? vs : 0.f;
                            acc0 = fmaf(vm, f0, acc0);
                            acc1 = fmaf(vm, f1, acc1);
                            acc2 = fmaf(vm, f2, acc2);
                            acc3 = fmaf(vm, f3, acc3);
                            if (rr == r3) break;
                            rr = (r1 > rr) ? r1 : ((r2 > rr) ? r2 : r3);
                        }
                    }
                }
            }
        }
#undef SPMM_ISSUE
    } else {
        // ---- tail path: generic per-edge loop (quarter 0 accumulates) ----
        cur = erow[base0];
        for (long e = base0; e < (long)E; ++e) {
            int r = erow[e];
            int c = ecol[e];
            float v = evalv[e] * scales[(unsigned)c];
            unsigned u = *(const unsigned*)(G8 + (((unsigned)c << 6) + voff));
            float f0 = (float)((int)(u << 24) >> 24);
            float f1 = (float)((int)(u << 16) >> 24);
            float f2 = (float)((int)(u << 8) >> 24);
            float f3 = (float)((int)u >> 24);
            if (r != cur) { flush(); cur = r; }
            float vm = (q == 0) ? v : 0.f;
            acc0 = fmaf(vm, f0, acc0);
            acc1 = fmaf(vm, f1, acc1);
            acc2 = fmaf(vm, f2, acc2);
            acc3 = fmaf(vm, f3, acc3);
        }
    }

    // last row may be shared with the next wave -> always atomic
    flush_atomic();
}

// Fallback if ws too small: fused f32 gather + shfl transform at flush.
__global__ __launch_bounds__(256) void k_fused(const float* __restrict__ feat,
                                               const int* __restrict__ erow,
                                               const int* __restrict__ ecol,
                                               const float* __restrict__ evalv,
                                               const float* __restrict__ W,
                                               float* __restrict__ out,
                                               int E, int epw) {
    __shared__ float Wt[64 * 64];
    for (int i = threadIdx.x; i < 4096; i += 256) {
        int c = i >> 6, f = i & 63;
        Wt[f * 64 + c] = W[i];
    }
    __syncthreads();

    int wave = blockIdx.x * 4 + (threadIdx.x >> 6);
    int lane = threadIdx.x & 63;
    long e0 = (long)wave * epw;
    if (e0 >= E) return;
    long e1 = e0 + epw; if (e1 > E) e1 = E;

    int cur = erow[e0];
    float acc = 0.f;
    for (long e = e0; e < e1; ++e) {
        int r = erow[e];
        int c = ecol[e];
        float v = evalv[e];
        float g = feat[((size_t)c << 6) | lane];
        if (r != cur) {
            float res = 0.f;
#pragma unroll
            for (int f = 0; f < 64; ++f)
                res += __shfl(acc, f, 64) * Wt[f * 64 + lane];
            atomicAdd(out + ((size_t)cur << 6) + lane, res);
            acc = 0.f;
            cur = r;
        }
        acc += v * g;
    }
    {
        float res = 0.f;
#pragma unroll
        for (int f = 0; f < 64; ++f)
            res += __shfl(acc, f, 64) * Wt[f * 64 + lane];
        atomicAdd(out + ((size_t)cur << 6) + lane, res);
    }
}

extern "C" void kernel_launch(void* const* d_in, const int* in_sizes, int n_in,
                              void* d_out, int out_size, void* d_ws, size_t ws_size,
                              hipStream_t stream) {
    const float* feat  = (const float*)d_in[0];
    const int*   erow  = (const int*)d_in[1];
    const int*   ecol  = (const int*)d_in[2];
    const float* evalv = (const float*)d_in[3];
    const float* W     = (const float*)d_in[4];
    const float* bias  = (const float*)d_in[5];
    float* out = (float*)d_out;

    int N = in_sizes[0] / 64;
    int E = in_sizes[1];

    size_t need = (size_t)N * 64 + (size_t)N * 4;   // int8 G + f32 scales
    if (ws_size >= need) {
        unsigned char* G8 = (unsigned char*)d_ws;
        float* scales = (float*)((char*)d_ws + (size_t)N * 64);
        int tiles = (N + 15) / 16;
        int gblocks = (tiles + 3) / 4;
        long total4 = (long)N * 16;
        int iblocks = (int)((total4 + 255) / 256);
        k_setup<<<gblocks + iblocks, 256, 0, stream>>>(feat, W, bias, G8, scales, out, N, gblocks);

        int nwaves = (E + 255) / 256;            // 256 edges/wave
        int nblocks = (nwaves + 3) / 4;
        k_spmm<<<nblocks, 256, 0, stream>>>(G8, scales, erow, ecol, evalv, bias, out, E);
    } else {
        long total4 = (long)N * 16;
        k_init<<<(int)((total4 + 255) / 256), 256, 0, stream>>>(bias, out, total4);
        int epw = (E + 8191) / 8192;
        if (epw < 32) epw = 32;
        int nwaves = (E + epw - 1) / epw;
        int nblocks = (nwaves + 3) / 4;
        k_fused<<<nblocks, 256, 0, stream>>>(feat, erow, ecol, evalv, W, out, E, epw);
    }
}